// Round 6
// baseline (177.193 us; speedup 1.0000x reference)
//
#include <hip/hip_runtime.h>
#include <cstdint>
#include <cstddef>

#define NROWS 32768   // 128 * 256 rows of D=1024
#define DDIM  1024
#define TPB   256     // 4 waves/block, 1 row per wave, 16 elems/thread
#define ROWS_PER_BLOCK 4

// ---------------- Threefry-2x32, add3-friendly, XOR-folded ----------------

__device__ __forceinline__ uint32_t rotl32(uint32_t x, uint32_t r) {
#if __has_builtin(__builtin_amdgcn_alignbit)
  return __builtin_amdgcn_alignbit(x, x, 32u - r);   // one v_alignbit_b32
#else
  return (x << r) | (x >> (32u - r));                // clang lowers to alignbit
#endif
}

// One threefry2x32 block, counter (0,c), x1init = c + k1 precomputed by caller.
// Returns x0 ^ x1 (JAX partitionable fold).
__device__ __forceinline__ uint32_t threefry_fold(uint32_t k0, uint32_t k1,
                                                  uint32_t x1init) {
  const uint32_t ks2 = k0 ^ k1 ^ 0x1BD11BDAu;
  uint32_t x1 = x1init;
  uint32_t x0 = k0 + x1;
  x1 = rotl32(x1, 13) ^ x0;
  x0 += x1; x1 = rotl32(x1, 15) ^ x0;
  x0 += x1; x1 = rotl32(x1, 26) ^ x0;
  x0 += x1; x1 = rotl32(x1,  6) ^ x0;
#define TF_GROUP(rA, rB, rC, rD, kA, kB)                  \
  x1 += (kB); x0 = (x0 + (kA)) + x1;                      \
  x1 = rotl32(x1, rA) ^ x0;                               \
  x0 += x1; x1 = rotl32(x1, rB) ^ x0;                     \
  x0 += x1; x1 = rotl32(x1, rC) ^ x0;                     \
  x0 += x1; x1 = rotl32(x1, rD) ^ x0;
  TF_GROUP(17, 29, 16, 24, k1,  ks2 + 1u)
  TF_GROUP(13, 15, 26,  6, ks2, k0  + 2u)
  TF_GROUP(17, 29, 16, 24, k0,  k1  + 3u)
  TF_GROUP(13, 15, 26,  6, k1,  ks2 + 4u)
#undef TF_GROUP
  x0 += ks2;
  x1 += k0 + 5u;
  return x0 ^ x1;
}

// ---- bits -> sqrt(2)*erfinv(uniform(lo,1)), poly evaluated directly in ----
// l = log2(1-u^2): w = -ln2*l, so Giles(w-2.5) == Q(l + 2.5/ln2) with the
// k-th coefficient scaled by (-ln2)^k. Saves the w mul + sub per call.
// Polys deg-4, sqrt(2)-prefolded (validated R4/R5: absmax 0.031 << 0.201).

__device__ __forceinline__ float bits_to_normal(uint32_t bits) {
  const float lo = -0.99999994f;               // nextafter(-1,0)
  float fn = (float)(bits >> 9);               // v_cvt_f32_u32, exact (<2^23)
  float u  = fmaf(fn, 0x1p-22f, lo);           // == XLA bitcast path, 1 rounding
  float t  = fmaf(-u, u, 1.0f);                // 1 - u^2 > 0
  float l  = __log2f(t);                       // v_log_f32
  float p;
  if (__builtin_expect(l > -7.2134752f, 1)) {  // w < 5 (warm)
    float z = l + 3.6067376f;                  // z = l + 2.5/ln2
    p = 7.1356157e-5f;                         // a4*(ln2)^4
    p = fmaf(p, z, 5.9047624e-4f);             // a3*(-ln2)^3
    p = fmaf(p, z, -2.8385851e-3f);            // a2*(ln2)^2
    p = fmaf(p, z, -2.4177163e-1f);            // a1*(-ln2)
    p = fmaf(p, z, 2.1233142f);                // a0
  } else {                                     // cold: |u|>0.9966, ~0.34%
    float w = -0.69314718f * l;
    float zz = sqrtf(w) - 3.0f;
    p = 8.1169400e-3f;
    p = fmaf(p, zz, -1.0779791e-2f);
    p = fmaf(p, zz, 1.3348601e-2f);
    p = fmaf(p, zz, 1.4165810f);
    p = fmaf(p, zz, 4.0064342f);
  }
  return p * u;
}

// ------- fused kernel: 1 wave == 1 row; rolled 4x4 element loop so the hot
// body (~6 KB) stays resident in I$ instead of streaming ~22 KB straight-line.
// Input float4 re-loaded per group (own row, L2-hot) to avoid runtime-indexed
// register arrays (-> scratch) while keeping the outer loop rolled.

__global__ __launch_bounds__(TPB) void NormalAugmenter_kernel(
    const float* __restrict__ in, float* __restrict__ out,
    uint32_t k1a, uint32_t k1b, uint32_t k2a, uint32_t k2b) {
  const uint32_t wave = threadIdx.x >> 6;               // 0..3
  const uint32_t lane = threadIdx.x & 63u;
  const uint32_t row  = blockIdx.x * ROWS_PER_BLOCK + wave;
  const size_t rowoff = (size_t)row * DDIM;
  const float4* vin  = reinterpret_cast<const float4*>(in + rowoff);
  float4*       vout = reinterpret_cast<float4*>(out + rowoff);

  // ---- pass 1: row stats (in-wave reduction only)
  float s = 0.0f, q = 0.0f;
  #pragma unroll
  for (int g = 0; g < 4; ++g) {
    float4 v = vin[lane + 64u * (uint32_t)g];
    s += (v.x + v.y) + (v.z + v.w);
    q = fmaf(v.x, v.x, fmaf(v.y, v.y, fmaf(v.z, v.z, fmaf(v.w, v.w, q))));
  }
  #pragma unroll
  for (int off = 32; off >= 1; off >>= 1) {
    s += __shfl_xor(s, off, 64);
    q += __shfl_xor(q, off, 64);
  }

  const float invD = 1.0f / (float)DDIM;
  const float mean = s * invD;
  float M2 = fmaf(-s, mean, q);                         // q - s^2/D
  M2 = fmaxf(M2, 0.0f);
  const float std_u = sqrtf(M2 * (1.0f / (DDIM - 1))); // unbiased (ddof=1)
  const float rstd  = rsqrtf(fmaf(M2, invD, 1e-5f));   // 1/sqrt(var_b + eps)
  const float hstd  = 0.5f * std_u;
  const float hmean = 0.5f * mean;
  const float noff  = -mean * rstd;

  // ---- pass 2: rolled over 4 groups of 4 elements
  const uint32_t cb = row * (uint32_t)DDIM + lane * 4u;
  uint32_t cA = cb + k1b;     // threefry x1-init for stream A, advances 256/group
  uint32_t cB = cb + k2b;     // stream B
  #pragma unroll 1
  for (uint32_t g = 0; g < 4; ++g) {
    float4 v = vin[lane + 64u * g];
    float xv[4] = {v.x, v.y, v.z, v.w};
    float o[4];
    #pragma unroll
    for (int j = 0; j < 4; ++j) {
      const float ea = bits_to_normal(threefry_fold(k1a, k1b, cA + (uint32_t)j));
      const float eb = bits_to_normal(threefry_fold(k2a, k2b, cB + (uint32_t)j));
      const float normed = fmaf(xv[j], rstd, noff);
      const float alpha  = fmaf(hstd, ea, 0.5f);   // 0.5*(1 + std*eps_a)
      const float beta   = fmaf(hstd, eb, hmean);  // 0.5*(mean + std*eps_b)
      o[j] = fmaf(alpha, normed, beta);
    }
    vout[lane + 64u * g] = make_float4(o[0], o[1], o[2], o[3]);
    cA += 256u;
    cB += 256u;
  }
}

// ---------------- host side ----------------

static void tf_host(uint32_t k0, uint32_t k1, uint32_t c0, uint32_t c1,
                    uint32_t& o0, uint32_t& o1) {
  auto rot = [](uint32_t x, uint32_t r) { return (x << r) | (x >> (32u - r)); };
  const uint32_t ks[3] = {k0, k1, k0 ^ k1 ^ 0x1BD11BDAu};
  const uint32_t rots[2][4] = {{13u,15u,26u,6u},{17u,29u,16u,24u}};
  uint32_t x0 = c0 + k0, x1 = c1 + k1;
  for (int i = 0; i < 5; ++i) {
    const uint32_t* rr = rots[i & 1];
    for (int j = 0; j < 4; ++j) { x0 += x1; x1 = rot(x1, rr[j]); x1 ^= x0; }
    x0 += ks[(i + 1) % 3];
    x1 += ks[(i + 2) % 3] + (uint32_t)(i + 1);
  }
  o0 = x0; o1 = x1;
}

extern "C" void kernel_launch(void* const* d_in, const int* in_sizes, int n_in,
                              void* d_out, int out_size, void* d_ws, size_t ws_size,
                              hipStream_t stream) {
  const float* in = (const float*)d_in[0];
  float* out = (float*)d_out;

  // jax.random.key(42) -> (0,42); split (threefry_partitionable):
  // k1 = threefry((0,42),(0,0)), k2 = threefry((0,42),(0,1))
  uint32_t k1a, k1b, k2a, k2b;
  tf_host(0u, 42u, 0u, 0u, k1a, k1b);
  tf_host(0u, 42u, 0u, 1u, k2a, k2b);

  NormalAugmenter_kernel<<<NROWS / ROWS_PER_BLOCK, TPB, 0, stream>>>(
      in, out, k1a, k1b, k2a, k2b);
}

// Round 7
// 139.843 us; speedup vs baseline: 1.2671x; 1.2671x over previous
//
#include <hip/hip_runtime.h>
#include <cstdint>
#include <cstddef>

#define NROWS 32768   // 128 * 256 rows of D=1024
#define DDIM  1024
#define TPB   256     // 4 waves/block, 1 row per wave, 16 elems/thread
#define ROWS_PER_BLOCK 4

// ---------------- Threefry-2x32, add3-friendly, XOR-folded ----------------

__device__ __forceinline__ uint32_t rotl32(uint32_t x, uint32_t r) {
#if __has_builtin(__builtin_amdgcn_alignbit)
  return __builtin_amdgcn_alignbit(x, x, 32u - r);   // one v_alignbit_b32
#else
  return (x << r) | (x >> (32u - r));
#endif
}

// One threefry2x32 block with counter (0,c); returns x0^x1 (JAX partitionable fold).
__device__ __forceinline__ uint32_t threefry_fold(uint32_t k0, uint32_t k1, uint32_t c) {
  const uint32_t ks2 = k0 ^ k1 ^ 0x1BD11BDAu;
  uint32_t x1 = c + k1;
  uint32_t x0 = k0 + x1;
  x1 = rotl32(x1, 13) ^ x0;
  x0 += x1; x1 = rotl32(x1, 15) ^ x0;
  x0 += x1; x1 = rotl32(x1, 26) ^ x0;
  x0 += x1; x1 = rotl32(x1,  6) ^ x0;
#define TF_GROUP(rA, rB, rC, rD, kA, kB)                  \
  x1 += (kB); x0 = (x0 + (kA)) + x1;                      \
  x1 = rotl32(x1, rA) ^ x0;                               \
  x0 += x1; x1 = rotl32(x1, rB) ^ x0;                     \
  x0 += x1; x1 = rotl32(x1, rC) ^ x0;                     \
  x0 += x1; x1 = rotl32(x1, rD) ^ x0;
  TF_GROUP(17, 29, 16, 24, k1,  ks2 + 1u)
  TF_GROUP(13, 15, 26,  6, ks2, k0  + 2u)
  TF_GROUP(17, 29, 16, 24, k0,  k1  + 3u)
  TF_GROUP(13, 15, 26,  6, k1,  ks2 + 4u)
#undef TF_GROUP
  x0 += ks2;
  x1 += k0 + 5u;
  return x0 ^ x1;
}

// ---- bits -> sqrt(2)*erfinv(uniform(lo,1)), poly evaluated directly in ----
// l = log2(1-u^2); Giles warm poly re-centered in l with coeffs scaled by
// (-ln2)^k; deg-4 both branches, sqrt(2)-prefolded. Validated: absmax 0.031.

__device__ __forceinline__ float bits_to_normal(uint32_t bits) {
  const float lo = -0.99999994f;               // nextafter(-1,0)
  float fn = (float)(bits >> 9);               // v_cvt_f32_u32, exact (<2^23)
  float u  = fmaf(fn, 0x1p-22f, lo);           // == XLA bitcast path, 1 rounding
  float t  = fmaf(-u, u, 1.0f);                // 1 - u^2 > 0
  float l  = __log2f(t);                       // v_log_f32
  float p;
  if (__builtin_expect(l > -7.2134752f, 1)) {  // w < 5 (warm)
    float z = l + 3.6067376f;                  // z = l + 2.5/ln2
    p = 7.1356157e-5f;
    p = fmaf(p, z, 5.9047624e-4f);
    p = fmaf(p, z, -2.8385851e-3f);
    p = fmaf(p, z, -2.4177163e-1f);
    p = fmaf(p, z, 2.1233142f);
  } else {                                     // cold: |u|>0.9966, ~0.34%
    float w = -0.69314718f * l;
    float zz = sqrtf(w) - 3.0f;
    p = 8.1169400e-3f;
    p = fmaf(p, zz, -1.0779791e-2f);
    p = fmaf(p, zz, 1.3348601e-2f);
    p = fmaf(p, zz, 1.4165810f);
    p = fmaf(p, zz, 4.0064342f);
  }
  return p * u;
}

// ---- fused kernel: 1 wave == 1 row, no LDS/barrier, fully unrolled.
// __launch_bounds__(256, 4): min 4 waves/EU -> VGPR cap 128, letting the
// allocator keep many independent threefry chains in flight (R5 chose 48
// VGPRs and serialized them; testing latency-exposure hypothesis).

__global__ __launch_bounds__(TPB, 4) void NormalAugmenter_kernel(
    const float* __restrict__ in, float* __restrict__ out,
    uint32_t k1a, uint32_t k1b, uint32_t k2a, uint32_t k2b) {
  const uint32_t wave = threadIdx.x >> 6;               // 0..3
  const uint32_t lane = threadIdx.x & 63u;
  const uint32_t row  = blockIdx.x * ROWS_PER_BLOCK + wave;
  const size_t rowoff = (size_t)row * DDIM;
  const float4* vin = reinterpret_cast<const float4*>(in + rowoff);

  float4 v0 = vin[lane];
  float4 v1 = vin[lane + 64u];
  float4 v2 = vin[lane + 128u];
  float4 v3 = vin[lane + 192u];
  float x[16] = {v0.x,v0.y,v0.z,v0.w, v1.x,v1.y,v1.z,v1.w,
                 v2.x,v2.y,v2.z,v2.w, v3.x,v3.y,v3.z,v3.w};

  // ---- row stats: in-wave reduction only
  float s = 0.0f, q = 0.0f;
  #pragma unroll
  for (int i = 0; i < 16; ++i) { s += x[i]; q = fmaf(x[i], x[i], q); }
  #pragma unroll
  for (int off = 32; off >= 1; off >>= 1) {
    s += __shfl_xor(s, off, 64);
    q += __shfl_xor(q, off, 64);
  }

  const float invD = 1.0f / (float)DDIM;
  const float mean = s * invD;
  float M2 = fmaf(-s, mean, q);                         // q - s^2/D
  M2 = fmaxf(M2, 0.0f);
  const float std_u = sqrtf(M2 * (1.0f / (DDIM - 1))); // unbiased (ddof=1)
  const float rstd  = rsqrtf(fmaf(M2, invD, 1e-5f));   // 1/sqrt(var_b + eps)
  const float hstd  = 0.5f * std_u;
  const float hmean = 0.5f * mean;
  const float noff  = -mean * rstd;

  // ---- per element: 2 threefry blocks -> 2 normals -> fused affine
  const uint32_t cb = row * (uint32_t)DDIM + lane * 4u;
  float o[16];
  #pragma unroll
  for (int i = 0; i < 16; ++i) {
    const uint32_t c = cb + (uint32_t)((i >> 2) << 8) + (uint32_t)(i & 3);
    const float ea = bits_to_normal(threefry_fold(k1a, k1b, c));
    const float eb = bits_to_normal(threefry_fold(k2a, k2b, c));
    const float normed = fmaf(x[i], rstd, noff);
    const float alpha  = fmaf(hstd, ea, 0.5f);   // 0.5*(1 + std*eps_a)
    const float beta   = fmaf(hstd, eb, hmean);  // 0.5*(mean + std*eps_b)
    o[i] = fmaf(alpha, normed, beta);
  }
  float4* vout = reinterpret_cast<float4*>(out + rowoff);
  vout[lane]        = make_float4(o[0],  o[1],  o[2],  o[3]);
  vout[lane + 64u]  = make_float4(o[4],  o[5],  o[6],  o[7]);
  vout[lane + 128u] = make_float4(o[8],  o[9],  o[10], o[11]);
  vout[lane + 192u] = make_float4(o[12], o[13], o[14], o[15]);
}

// ---------------- host side ----------------

static void tf_host(uint32_t k0, uint32_t k1, uint32_t c0, uint32_t c1,
                    uint32_t& o0, uint32_t& o1) {
  auto rot = [](uint32_t x, uint32_t r) { return (x << r) | (x >> (32u - r)); };
  const uint32_t ks[3] = {k0, k1, k0 ^ k1 ^ 0x1BD11BDAu};
  const uint32_t rots[2][4] = {{13u,15u,26u,6u},{17u,29u,16u,24u}};
  uint32_t x0 = c0 + k0, x1 = c1 + k1;
  for (int i = 0; i < 5; ++i) {
    const uint32_t* rr = rots[i & 1];
    for (int j = 0; j < 4; ++j) { x0 += x1; x1 = rot(x1, rr[j]); x1 ^= x0; }
    x0 += ks[(i + 1) % 3];
    x1 += ks[(i + 2) % 3] + (uint32_t)(i + 1);
  }
  o0 = x0; o1 = x1;
}

extern "C" void kernel_launch(void* const* d_in, const int* in_sizes, int n_in,
                              void* d_out, int out_size, void* d_ws, size_t ws_size,
                              hipStream_t stream) {
  const float* in = (const float*)d_in[0];
  float* out = (float*)d_out;

  // jax.random.key(42) -> (0,42); split (threefry_partitionable):
  // k1 = threefry((0,42),(0,0)), k2 = threefry((0,42),(0,1))
  uint32_t k1a, k1b, k2a, k2b;
  tf_host(0u, 42u, 0u, 0u, k1a, k1b);
  tf_host(0u, 42u, 0u, 1u, k2a, k2b);

  NormalAugmenter_kernel<<<NROWS / ROWS_PER_BLOCK, TPB, 0, stream>>>(
      in, out, k1a, k1b, k2a, k2b);
}